// Round 1
// baseline (4074.359 us; speedup 1.0000x reference)
//
#include <hip/hip_runtime.h>
#include <cstdint>

// ---------------------------------------------------------------------------
// MaskedDeepRNN: 2-layer masked LSTM, B=64 T=512 D_IN=256 H=512 G=4H=2048.
// Plan:
//   prep : masked weights -> fp16, bias sums, x transposed to [t*64+b][256] fp16
//   proj0: xW0 = x @ Wih0m^T + b   (MFMA fp16, fp32 acc, out fp16 [T*B][G])
//   rec0 : 512 sequential steps, persistent-weight "XCD island" kernel
//   proj1: xW1 = h0 @ Wih1m^T + b
//   rec1 : same, writes final h1[t=511] to d_out (fp32)
// ---------------------------------------------------------------------------

typedef _Float16 f16;
typedef _Float16 half8 __attribute__((ext_vector_type(8)));
typedef _Float16 half4v __attribute__((ext_vector_type(4)));
typedef float floatx4 __attribute__((ext_vector_type(4)));

#define B_ 64
#define T_ 512
#define DIN_ 256
#define H_ 512
#define G_ 2048

// workspace layout (bytes)
static const size_t OFF_CNT  = 0;                       // 2 KB: barrier counters (128B strided)
static const size_t OFF_HB   = 2048;                    // 128 KB: h double buffers, 8 isl x 2 x [8][512] f16
static const size_t OFF_XT   = 2048 + 131072;           // 16 MB: x fp16, rows t*64+b
static const size_t OFF_WIH0 = OFF_XT + 16777216;       // 1 MB
static const size_t OFF_WHH0 = OFF_WIH0 + 1048576;      // 2 MB
static const size_t OFF_WIH1 = OFF_WHH0 + 2097152;      // 2 MB
static const size_t OFF_WHH1 = OFF_WIH1 + 2097152;      // 2 MB
static const size_t OFF_B0   = OFF_WHH1 + 2097152;      // 8 KB
static const size_t OFF_B1   = OFF_B0 + 8192;           // 8 KB
static const size_t OFF_XW   = OFF_B1 + 8192;           // 128 MB: xW fp16 [T*B][G] (reused by both layers)
static const size_t OFF_H0   = OFF_XW + 134217728;      // 32 MB: h0 fp16 [T*B][H]
// total ~183 MB

// ---------------------------------------------------------------- prep ------
__global__ void k_maskw(const float* __restrict__ w, const float* __restrict__ m,
                        f16* __restrict__ o, int n4) {
    int i = blockIdx.x * 256 + threadIdx.x;
    if (i < n4) {
        const float4 wv = ((const float4*)w)[i];
        const float4 mv = ((const float4*)m)[i];
        half4v h = { (f16)(wv.x * mv.x), (f16)(wv.y * mv.y),
                     (f16)(wv.z * mv.z), (f16)(wv.w * mv.w) };
        ((half4v*)o)[i] = h;
    }
}

__global__ void k_bias(const float* __restrict__ a, const float* __restrict__ b,
                       float* __restrict__ o) {
    int i = blockIdx.x * 256 + threadIdx.x;
    if (i < G_) o[i] = a[i] + b[i];
}

// x [b][t][k] fp32 -> xt [(t*64+b)][k] fp16
__global__ void k_xt(const float* __restrict__ x, f16* __restrict__ xt) {
    const int idx = blockIdx.x * 256 + threadIdx.x;  // 2097152 total, 4 elems each
    const int k4 = idx & 63;
    const int t  = (idx >> 6) & 511;
    const int b  = idx >> 15;
    const float4 v = *(const float4*)(x + (((size_t)b * T_ + t) * DIN_) + k4 * 4);
    half4v h = { (f16)v.x, (f16)v.y, (f16)v.z, (f16)v.w };
    *(half4v*)(xt + ((size_t)t * B_ + b) * DIN_ + k4 * 4) = h;
}

// ---------------------------------------------------- projection GEMM -------
// C[m][n] = A[m][:K] . Bw[n][:K] + bias[n], C fp16. M=32768, N=2048.
// 128x128 tile / WG (4 waves x 64x64), BK=32, LDS double buffer, 1 sync/iter.
template<int K>
__global__ __launch_bounds__(256, 2) void proj_kernel(
    const f16* __restrict__ A, const f16* __restrict__ Bw,
    const float* __restrict__ bias, f16* __restrict__ C)
{
    __shared__ f16 As[2][128][40];   // pad 32->40 halves: 16B-aligned rows, banks spread
    __shared__ f16 Bs[2][128][40];
    const int tid  = threadIdx.x;
    const int nt   = blockIdx.x & 15;
    const int mt   = blockIdx.x >> 4;
    const size_t m0 = (size_t)mt * 128, n0 = (size_t)nt * 128;
    const int wave = tid >> 6, lane = tid & 63, lm = lane & 15, quad = lane >> 4;
    const int wm = (wave >> 1) * 64, wn = (wave & 1) * 64;
    const int srow = tid >> 1, soff = (tid & 1) * 16;

    const f16* Ap = A  + (m0 + srow) * K + soff;
    const f16* Bp = Bw + (n0 + srow) * K + soff;

    floatx4 acc[4][4] = {};
    int4 ra0 = ((const int4*)Ap)[0], ra1 = ((const int4*)Ap)[1];
    int4 rb0 = ((const int4*)Bp)[0], rb1 = ((const int4*)Bp)[1];

    const int NCH = K / 32;
    for (int ch = 0; ch < NCH; ++ch) {
        const int buf = ch & 1;
        *(int4*)&As[buf][srow][soff]     = ra0;
        *(int4*)&As[buf][srow][soff + 8] = ra1;
        *(int4*)&Bs[buf][srow][soff]     = rb0;
        *(int4*)&Bs[buf][srow][soff + 8] = rb1;
        __syncthreads();
        if (ch + 1 < NCH) {              // prefetch overlaps compute phase
            const f16* An = Ap + (ch + 1) * 32;
            const f16* Bn = Bp + (ch + 1) * 32;
            ra0 = ((const int4*)An)[0]; ra1 = ((const int4*)An)[1];
            rb0 = ((const int4*)Bn)[0]; rb1 = ((const int4*)Bn)[1];
        }
        half8 av[4], bv[4];
#pragma unroll
        for (int s = 0; s < 4; ++s) {
            av[s] = *(const half8*)&As[buf][wm + s * 16 + lm][quad * 8];
            bv[s] = *(const half8*)&Bs[buf][wn + s * 16 + lm][quad * 8];
        }
#pragma unroll
        for (int ms = 0; ms < 4; ++ms)
#pragma unroll
            for (int ns = 0; ns < 4; ++ns)
                acc[ms][ns] = __builtin_amdgcn_mfma_f32_16x16x32_f16(
                    av[ms], bv[ns], acc[ms][ns], 0, 0, 0);
        __syncthreads();
    }
    // epilogue: C layout col=lane&15, row=quad*4+reg
    float bs[4];
#pragma unroll
    for (int ns = 0; ns < 4; ++ns) bs[ns] = bias[n0 + wn + ns * 16 + lm];
#pragma unroll
    for (int ms = 0; ms < 4; ++ms) {
#pragma unroll
        for (int r = 0; r < 4; ++r) {
            const size_t row = m0 + wm + ms * 16 + quad * 4 + r;
            f16* crow = C + row * G_ + n0 + wn + lm;
#pragma unroll
            for (int ns = 0; ns < 4; ++ns)
                crow[ns * 16] = (f16)(acc[ms][ns][r] + bs[ns]);
        }
    }
}

// ------------------------------------------------------- recurrent ----------
// 8 islands (blockIdx%8 -> XCD under round-robin) x 32 WGs x 256 thr.
// Island i owns batches 8i..8i+7. WG 'mem' owns hidden units jb=mem*16..+16
// (gate rows gt*512+jb+jj for gt=0..3). W_hh fragments persist in VGPRs.
// Per step: stage h[8][512] f16 via agent-atomic loads -> LDS; each wave does
// its K-quarter, 16 MFMAs; partials summed via LDS; 128 thr do gate math;
// h written back with agent-atomic stores; island barrier on atomic counter.
template<int WRITE_H0>
__global__ __launch_bounds__(256, 1) void rec_kernel(
    const f16* __restrict__ xW,      // [T*B][G] fp16 (bias included)
    const f16* __restrict__ Whh,     // [G][H] fp16 masked
    f16* __restrict__ h0_all,        // [T*B][H] (layer0) or unused
    float* __restrict__ dout,        // [B][H] (layer1) or unused
    uint32_t* __restrict__ hbufs,    // 8 isl x 2 bufs x 2048 uints ([8][512] f16)
    uint32_t* __restrict__ cnt)      // per-island, 128B strided
{
    __shared__ f16 hl[8][520];           // h staged, padded rows (1040B, 16B-aligned)
    __shared__ float glp[4][4][16][8];   // [kquarter][gate][jj][b] partial sums
    __shared__ float cs[128];            // cell state c[jj][b]
    const int tid  = threadIdx.x;
    const int isl  = blockIdx.x & 7, mem = blockIdx.x >> 3;
    const int jb   = mem * 16, b0 = isl * 8;
    const int wave = tid >> 6, lane = tid & 63, lm = lane & 15, quad = lane >> 4;

    // persistent A fragments: a[gt][kk] covers rows gt*512+jb+lm, k = wave*128+kk*32+quad*8..+8
    half8 a[4][4];
    {
        const int kbase = wave * 128 + quad * 8;
#pragma unroll
        for (int gt = 0; gt < 4; ++gt) {
            const f16* wr = Whh + (size_t)(gt * 512 + jb + lm) * H_ + kbase;
#pragma unroll
            for (int kk = 0; kk < 4; ++kk)
                a[gt][kk] = *(const half8*)(wr + kk * 32);
        }
    }
    if (tid < 128) cs[tid] = 0.f;

    const int eb = tid >> 4, ejj = tid & 15;          // epilogue thread -> (batch, j)
    uint32_t* hb_isl = hbufs + (size_t)isl * 4096;    // 2 bufs x 2048 uints
    uint32_t* mycnt  = cnt + isl * 32;
    const int hrow   = lm < 8 ? lm : 7;               // cols 8..15 are discarded

    for (int t = 0; t < T_; ++t) {
        // ---- stage h[t] (written by island peers last step; agent-coherent)
        {
            const uint32_t* hb = hb_isl + (t & 1) * 2048;
#pragma unroll
            for (int i = 0; i < 8; ++i) {
                const int u = i * 256 + tid;          // row = i, col = tid
                const uint32_t v = __hip_atomic_load(hb + u, __ATOMIC_RELAXED,
                                                     __HIP_MEMORY_SCOPE_AGENT);
                *(uint32_t*)&hl[u >> 8][(u & 255) * 2] = v;
            }
        }
        // ---- prefetch this thread's xW gates (drains at the sync, L2-hot)
        float xw0, xw1, xw2, xw3;
        if (tid < 128) {
            const f16* p = xW + ((size_t)t * B_ + b0 + eb) * G_ + jb + ejj;
            xw0 = (float)p[0];    xw1 = (float)p[512];
            xw2 = (float)p[1024]; xw3 = (float)p[1536];
        }
        __syncthreads();
        // ---- MFMA: this wave's K-quarter, 4 gate tiles
        floatx4 acc[4] = {};
        {
            const f16* br = &hl[hrow][wave * 128 + quad * 8];
#pragma unroll
            for (int kk = 0; kk < 4; ++kk) {
                const half8 b = *(const half8*)(br + kk * 32);
#pragma unroll
                for (int gt = 0; gt < 4; ++gt)
                    acc[gt] = __builtin_amdgcn_mfma_f32_16x16x32_f16(
                        a[gt][kk], b, acc[gt], 0, 0, 0);
            }
        }
        if (lm < 8) {
#pragma unroll
            for (int gt = 0; gt < 4; ++gt)
#pragma unroll
                for (int r = 0; r < 4; ++r)
                    glp[wave][gt][quad * 4 + r][lm] = acc[gt][r];
        }
        __syncthreads();
        // ---- gate nonlinearities + state update (128 threads)
        if (tid < 128) {
            float gi = xw0, gf = xw1, gg = xw2, go = xw3;
#pragma unroll
            for (int w = 0; w < 4; ++w) {
                gi += glp[w][0][ejj][eb];
                gf += glp[w][1][ejj][eb];
                gg += glp[w][2][ejj][eb];
                go += glp[w][3][ejj][eb];
            }
            const float i_ = 1.f / (1.f + __expf(-gi));
            const float f_ = 1.f / (1.f + __expf(-gf));
            const float gc = fminf(fmaxf(gg, -20.f), 20.f);
            const float e2 = __expf(2.f * gc);
            const float g_ = (e2 - 1.f) / (e2 + 1.f);
            const float o_ = 1.f / (1.f + __expf(-go));
            const float cn = f_ * cs[tid] + i_ * g_;
            cs[tid] = cn;
            const float cc  = fminf(fmaxf(cn, -20.f), 20.f);
            const float e2c = __expf(2.f * cc);
            const float th  = (e2c - 1.f) / (e2c + 1.f);
            const float hn  = o_ * th;
            // pack pairs along j (adjacent lanes) and store agent-coherent
            const float ho = __shfl_xor(hn, 1);
            if ((ejj & 1) == 0) {
                union { f16 h[2]; uint32_t u; } pk;
                pk.h[0] = (f16)hn; pk.h[1] = (f16)ho;
                uint32_t* dst = hb_isl + ((t + 1) & 1) * 2048
                              + (eb * H_ + jb + ejj) / 2;
                __hip_atomic_store(dst, pk.u, __ATOMIC_RELAXED,
                                   __HIP_MEMORY_SCOPE_AGENT);
            }
            if (WRITE_H0) {
                h0_all[((size_t)t * B_ + b0 + eb) * H_ + jb + ejj] = (f16)hn;
            } else if (t == T_ - 1) {
                dout[(size_t)(b0 + eb) * H_ + jb + ejj] = hn;
            }
        }
        // ---- island barrier: stores complete (vmcnt drained at syncthreads)
        // before thread0's RMW; readers' loads are agent-atomic -> no fences.
        __syncthreads();
        if (tid == 0) {
            __hip_atomic_fetch_add(mycnt, 1u, __ATOMIC_RELAXED,
                                   __HIP_MEMORY_SCOPE_AGENT);
            const uint32_t target = 32u * (uint32_t)(t + 1);
            while (__hip_atomic_load(mycnt, __ATOMIC_RELAXED,
                                     __HIP_MEMORY_SCOPE_AGENT) < target)
                __builtin_amdgcn_s_sleep(1);
        }
        __syncthreads();
    }
}

// ------------------------------------------------------------ launcher ------
extern "C" void kernel_launch(void* const* d_in, const int* in_sizes, int n_in,
                              void* d_out, int out_size, void* d_ws, size_t ws_size,
                              hipStream_t stream) {
    const float* x    = (const float*)d_in[0];
    const float* Wih0 = (const float*)d_in[1];
    const float* Whh0 = (const float*)d_in[2];
    const float* bih0 = (const float*)d_in[3];
    const float* bhh0 = (const float*)d_in[4];
    const float* mih0 = (const float*)d_in[5];
    const float* mhh0 = (const float*)d_in[6];
    const float* Wih1 = (const float*)d_in[7];
    const float* Whh1 = (const float*)d_in[8];
    const float* bih1 = (const float*)d_in[9];
    const float* bhh1 = (const float*)d_in[10];
    const float* mih1 = (const float*)d_in[11];
    const float* mhh1 = (const float*)d_in[12];

    char* ws = (char*)d_ws;
    uint32_t* cnt0 = (uint32_t*)(ws + OFF_CNT);
    uint32_t* cnt1 = (uint32_t*)(ws + OFF_CNT + 1024);
    uint32_t* hb   = (uint32_t*)(ws + OFF_HB);
    f16*   xt   = (f16*)(ws + OFF_XT);
    f16*   wih0 = (f16*)(ws + OFF_WIH0);
    f16*   whh0 = (f16*)(ws + OFF_WHH0);
    f16*   wih1 = (f16*)(ws + OFF_WIH1);
    f16*   whh1 = (f16*)(ws + OFF_WHH1);
    float* bs0  = (float*)(ws + OFF_B0);
    float* bs1  = (float*)(ws + OFF_B1);
    f16*   xw   = (f16*)(ws + OFF_XW);
    f16*   h0a  = (f16*)(ws + OFF_H0);
    float* out  = (float*)d_out;

    // zero barrier counters + h double buffers (ws is poisoned every call)
    hipMemsetAsync(ws, 0, OFF_HB + 131072, stream);

    k_maskw<<<512,  256, 0, stream>>>(Wih0, mih0, wih0, G_ * DIN_ / 4);
    k_maskw<<<1024, 256, 0, stream>>>(Whh0, mhh0, whh0, G_ * H_ / 4);
    k_maskw<<<1024, 256, 0, stream>>>(Wih1, mih1, wih1, G_ * H_ / 4);
    k_maskw<<<1024, 256, 0, stream>>>(Whh1, mhh1, whh1, G_ * H_ / 4);
    k_bias<<<8, 256, 0, stream>>>(bih0, bhh0, bs0);
    k_bias<<<8, 256, 0, stream>>>(bih1, bhh1, bs1);
    k_xt<<<8192, 256, 0, stream>>>(x, xt);

    proj_kernel<256><<<4096, 256, 0, stream>>>(xt, wih0, bs0, xw);
    rec_kernel<1><<<256, 256, 0, stream>>>(xw, whh0, h0a, nullptr, hb, cnt0);
    proj_kernel<512><<<4096, 256, 0, stream>>>(h0a, wih1, bs1, xw);
    hipMemsetAsync(ws + OFF_HB, 0, 131072, stream);  // reset h buffers for layer 1
    rec_kernel<0><<<256, 256, 0, stream>>>(xw, whh1, nullptr, out, hb, cnt1);

    (void)in_sizes; (void)n_in; (void)out_size; (void)ws_size;
}

// Round 2
// 1397.984 us; speedup vs baseline: 2.9145x; 2.9145x over previous
//
#include <hip/hip_runtime.h>
#include <cstdint>

// ---------------------------------------------------------------------------
// MaskedDeepRNN fused: 2-layer masked LSTM, B=64 T=512 D_IN=256 H=512 G=2048.
// Single persistent kernel, 512 WGs (2/CU):
//   blocks   0..255 = layer 0 (weights Wih0[64x256] + Whh0[64x512] in VGPRs)
//   blocks 256..511 = layer 1 (weights Wih1[64x512] + Whh1[64x512] in VGPRs)
// Islands of 32 WGs per 8-batch slice (blockIdx&7 -> XCD). Layer-1 runs with
// lag 1 behind layer-0, consuming h0[t] through a 4-slot L3 ring. All
// inter-WG exchange: relaxed agent atomics; data stores are drained
// (__syncthreads => vmcnt(0)) before the per-WG step flag is published.
// Barrier = 32 flag stores (no RMW contention) + one 64-lane parallel poll.
// ---------------------------------------------------------------------------

typedef _Float16 f16;
typedef _Float16 half8 __attribute__((ext_vector_type(8)));
typedef _Float16 half4v __attribute__((ext_vector_type(4)));
typedef float floatx4 __attribute__((ext_vector_type(4)));

#define B_ 64
#define T_ 512
#define DIN_ 256
#define H_ 512
#define G_ 2048

// workspace layout (bytes)
static const size_t OFF_FLAGS = 0;                              // 2 lay x 8 isl x 32 flags x 64B = 32 KB
static const size_t OFF_H0B   = 32768;                          // 8 isl x 4 slots x 8KB = 256 KB
static const size_t OFF_H1B   = OFF_H0B + 262144;               // 8 isl x 2 slots x 8KB = 128 KB
static const size_t OFF_WIH0  = OFF_H1B + 131072;               // 1 MB  (425984)
static const size_t OFF_WHH0  = OFF_WIH0 + (size_t)G_ * DIN_ * 2;
static const size_t OFF_WIH1  = OFF_WHH0 + (size_t)G_ * H_ * 2;
static const size_t OFF_WHH1  = OFF_WIH1 + (size_t)G_ * H_ * 2;
static const size_t OFF_B0    = OFF_WHH1 + (size_t)G_ * H_ * 2;
static const size_t OFF_B1    = OFF_B0 + 8192;
static const size_t ZERO_BYTES = OFF_WIH0;                      // flags + h rings

__device__ __forceinline__ uint32_t ald(const uint32_t* p) {
    return __hip_atomic_load(p, __ATOMIC_RELAXED, __HIP_MEMORY_SCOPE_AGENT);
}
__device__ __forceinline__ void ast(uint32_t* p, uint32_t v) {
    __hip_atomic_store(p, v, __ATOMIC_RELAXED, __HIP_MEMORY_SCOPE_AGENT);
}

// ---------------------------------------------------------------- prep ------
__global__ void k_maskw(const float* __restrict__ w, const float* __restrict__ m,
                        f16* __restrict__ o, int n4) {
    int i = blockIdx.x * 256 + threadIdx.x;
    if (i < n4) {
        const float4 wv = ((const float4*)w)[i];
        const float4 mv = ((const float4*)m)[i];
        half4v h = { (f16)(wv.x * mv.x), (f16)(wv.y * mv.y),
                     (f16)(wv.z * mv.z), (f16)(wv.w * mv.w) };
        ((half4v*)o)[i] = h;
    }
}

__global__ void k_bias(const float* __restrict__ a, const float* __restrict__ b,
                       float* __restrict__ o) {
    int i = blockIdx.x * 256 + threadIdx.x;
    if (i < G_) o[i] = a[i] + b[i];
}

// ------------------------------------------------------------ helpers -------
__device__ __forceinline__ void poll_flags(const uint32_t* ownF, uint32_t town,
                                           const uint32_t* crossF, uint32_t tcr,
                                           int lane) {
    // lanes 0..31 watch own-island flags, 32..63 the partner layer's island
    const uint32_t* p = (lane < 32) ? (ownF + (size_t)lane * 16)
                                    : (crossF + (size_t)(lane - 32) * 16);
    const uint32_t tgt = (lane < 32) ? town : tcr;
    while (true) {
        const uint32_t v = ald(p);
        if (__all((int)(v >= tgt))) break;
        __builtin_amdgcn_s_sleep(1);
    }
}

__device__ __forceinline__ float lstm_cell(float gi, float gf, float gg, float go,
                                           float& c) {
    const float i_ = 1.f / (1.f + __expf(-gi));
    const float f_ = 1.f / (1.f + __expf(-gf));
    const float gc = fminf(fmaxf(gg, -20.f), 20.f);
    const float e2 = __expf(2.f * gc);
    const float g_ = (e2 - 1.f) / (e2 + 1.f);
    const float o_ = 1.f / (1.f + __expf(-go));
    c = f_ * c + i_ * g_;
    const float cc  = fminf(fmaxf(c, -20.f), 20.f);
    const float e2c = __expf(2.f * cc);
    return o_ * (e2c - 1.f) / (e2c + 1.f);
}

// -------------------------------------------------------- fused kernel ------
__global__ __launch_bounds__(256, 2) void fused_rnn(
    const float* __restrict__ x,
    const f16* __restrict__ Wih0, const f16* __restrict__ Whh0,
    const float* __restrict__ bs0,
    const f16* __restrict__ Wih1, const f16* __restrict__ Whh1,
    const float* __restrict__ bs1,
    float* __restrict__ dout,
    uint32_t* __restrict__ h0b,      // [8 isl][4 slots][2048 dw] f16 pairs
    uint32_t* __restrict__ h1b,      // [8 isl][2 slots][2048 dw]
    uint32_t* __restrict__ flags)    // [2 lay][8 isl][32 x 16 dw]
{
    __shared__ f16 bl0[8][520];            // B-operand: own-layer h
    __shared__ f16 bl1[8][520];            // B-operand: x (L0) or h0 (L1)
    __shared__ float glp[4][4][16][9];     // [kquarter][gate][jj][b] partials (pad 9)

    const int tid  = threadIdx.x;
    const int bid  = blockIdx.x;
    const int isl  = bid & 7;              // -> XCD under round-robin
    const int mem  = (bid >> 3) & 31;
    const int layer = bid >> 8;
    const int jb = mem * 16, b0 = isl * 8;
    const int wave = tid >> 6, lane = tid & 63, lm = lane & 15, quad = lane >> 4;
    const int eb = tid >> 4, ejj = tid & 15;
    const int hrow = lm < 8 ? lm : 7;      // cols 8..15 duplicate row 7 (discarded)

    uint32_t* ownF   = flags + (size_t)(layer * 8 + isl) * 512;
    uint32_t* crossF = flags + (size_t)((1 - layer) * 8 + isl) * 512;
    uint32_t* h0i = h0b + (size_t)isl * 4 * 2048;
    uint32_t* h1i = h1b + (size_t)isl * 2 * 2048;

    if (layer == 0) {
        // ---- persistent A fragments: Whh0 (K=512) + Wih0 (K=256)
        half8 ah[4][4], ai[4][2];
        {
            const int kb  = wave * 128 + quad * 8;
            const int kbx = wave * 64 + quad * 8;
#pragma unroll
            for (int gt = 0; gt < 4; ++gt) {
                const f16* wr = Whh0 + (size_t)(gt * 512 + jb + lm) * H_ + kb;
                const f16* xr = Wih0 + (size_t)(gt * 512 + jb + lm) * DIN_ + kbx;
#pragma unroll
                for (int kk = 0; kk < 4; ++kk) ah[gt][kk] = *(const half8*)(wr + kk * 32);
#pragma unroll
                for (int kk = 0; kk < 2; ++kk) ai[gt][kk] = *(const half8*)(xr + kk * 32);
            }
        }
        float bias[4];
#pragma unroll
        for (int g = 0; g < 4; ++g) bias[g] = bs0[g * 512 + jb + ejj];
        float c = 0.f;
        // x[t] slice for this island: thread -> (batch=tid>>5, k0=(tid&31)*8)
        const float* xp = x + (size_t)(b0 + (tid >> 5)) * T_ * DIN_ + (tid & 31) * 8;
        float4 xa = *(const float4*)xp;            // x[0] preloaded
        float4 xb = *(const float4*)(xp + 4);

        for (int t = 0; t < T_; ++t) {
            // own peers done with step t-1; L1 done with step t-4 (ring safety)
            if (wave == 0)
                poll_flags(ownF, (uint32_t)t, crossF,
                           t >= 3 ? (uint32_t)(t - 3) : 0u, lane);
            __syncthreads();
            // ---- stage h0[t-1] (ring slot (t-1)&3) + x[t]; prefetch x[t+1]
            {
                const uint32_t* hb = h0i + (size_t)((t + 3) & 3) * 2048;
                uint32_t va[8];
#pragma unroll
                for (int i = 0; i < 8; ++i) va[i] = ald(hb + i * 256 + tid);
                half8 hx = { (f16)xa.x, (f16)xa.y, (f16)xa.z, (f16)xa.w,
                             (f16)xb.x, (f16)xb.y, (f16)xb.z, (f16)xb.w };
                *(half8*)&bl1[tid >> 5][(tid & 31) * 8] = hx;
                const size_t tn = (size_t)(t + 1 < T_ ? t + 1 : t) * DIN_;
                xa = *(const float4*)(xp + tn);    // L2-hot, hides under h latency
                xb = *(const float4*)(xp + tn + 4);
#pragma unroll
                for (int i = 0; i < 8; ++i) {
                    const int u = i * 256 + tid;
                    *(uint32_t*)&bl0[u >> 8][(u & 255) * 2] = va[i];
                }
            }
            __syncthreads();
            // ---- MFMA: gates = h.Whh (16) + x.Wih (8)
            floatx4 acc[4] = {};
            {
                const f16* br0 = &bl0[hrow][wave * 128 + quad * 8];
                const f16* br1 = &bl1[hrow][wave * 64 + quad * 8];
#pragma unroll
                for (int kk = 0; kk < 4; ++kk) {
                    const half8 bv = *(const half8*)(br0 + kk * 32);
#pragma unroll
                    for (int gt = 0; gt < 4; ++gt)
                        acc[gt] = __builtin_amdgcn_mfma_f32_16x16x32_f16(
                            ah[gt][kk], bv, acc[gt], 0, 0, 0);
                }
#pragma unroll
                for (int kk = 0; kk < 2; ++kk) {
                    const half8 bv = *(const half8*)(br1 + kk * 32);
#pragma unroll
                    for (int gt = 0; gt < 4; ++gt)
                        acc[gt] = __builtin_amdgcn_mfma_f32_16x16x32_f16(
                            ai[gt][kk], bv, acc[gt], 0, 0, 0);
                }
            }
            if (lm < 8)
#pragma unroll
                for (int gt = 0; gt < 4; ++gt)
#pragma unroll
                    for (int r = 0; r < 4; ++r)
                        glp[wave][gt][quad * 4 + r][lm] = acc[gt][r];
            __syncthreads();
            // ---- gate math + publish h0[t] into ring slot t&3
            if (tid < 128) {
                float gi = bias[0], gf = bias[1], gg = bias[2], go = bias[3];
#pragma unroll
                for (int w = 0; w < 4; ++w) {
                    gi += glp[w][0][ejj][eb]; gf += glp[w][1][ejj][eb];
                    gg += glp[w][2][ejj][eb]; go += glp[w][3][ejj][eb];
                }
                const float hn = lstm_cell(gi, gf, gg, go, c);
                const float ho = __shfl_xor(hn, 1);
                if (!(ejj & 1)) {
                    union { f16 h[2]; uint32_t u; } pk;
                    pk.h[0] = (f16)hn; pk.h[1] = (f16)ho;
                    ast(h0i + (size_t)(t & 3) * 2048 + (eb * H_ + jb + ejj) / 2, pk.u);
                }
            }
            __syncthreads();                       // drains h stores (vmcnt 0)
            if (tid == 0) ast(ownF + mem * 16, (uint32_t)(t + 1));
        }
    } else {
        // ---- layer 1: Whh1 + Wih1, both K=512, gates = h1.Whh1 + h0.Wih1
        half8 ah[4][4], ai[4][4];
        {
            const int kb = wave * 128 + quad * 8;
#pragma unroll
            for (int gt = 0; gt < 4; ++gt) {
                const f16* wr = Whh1 + (size_t)(gt * 512 + jb + lm) * H_ + kb;
                const f16* xr = Wih1 + (size_t)(gt * 512 + jb + lm) * H_ + kb;
#pragma unroll
                for (int kk = 0; kk < 4; ++kk) {
                    ah[gt][kk] = *(const half8*)(wr + kk * 32);
                    ai[gt][kk] = *(const half8*)(xr + kk * 32);
                }
            }
        }
        float bias[4];
#pragma unroll
        for (int g = 0; g < 4; ++g) bias[g] = bs1[g * 512 + jb + ejj];
        float c = 0.f;

        for (int t = 0; t < T_; ++t) {
            // own peers done with step t-1; L0 has published h0[t] (flag t+1)
            if (wave == 0)
                poll_flags(ownF, (uint32_t)t, crossF, (uint32_t)(t + 1), lane);
            __syncthreads();
            // ---- stage h1[t-1] (parity) + h0[t] (ring slot t&3)
            {
                const uint32_t* hb = h1i + (size_t)((t + 1) & 1) * 2048;
                const uint32_t* gb = h0i + (size_t)(t & 3) * 2048;
                uint32_t va[8], vb[8];
#pragma unroll
                for (int i = 0; i < 8; ++i) va[i] = ald(hb + i * 256 + tid);
#pragma unroll
                for (int i = 0; i < 8; ++i) vb[i] = ald(gb + i * 256 + tid);
#pragma unroll
                for (int i = 0; i < 8; ++i) {
                    const int u = i * 256 + tid;
                    *(uint32_t*)&bl0[u >> 8][(u & 255) * 2] = va[i];
                    *(uint32_t*)&bl1[u >> 8][(u & 255) * 2] = vb[i];
                }
            }
            __syncthreads();
            floatx4 acc[4] = {};
            {
                const f16* br0 = &bl0[hrow][wave * 128 + quad * 8];
                const f16* br1 = &bl1[hrow][wave * 128 + quad * 8];
#pragma unroll
                for (int kk = 0; kk < 4; ++kk) {
                    const half8 b0v = *(const half8*)(br0 + kk * 32);
                    const half8 b1v = *(const half8*)(br1 + kk * 32);
#pragma unroll
                    for (int gt = 0; gt < 4; ++gt) {
                        acc[gt] = __builtin_amdgcn_mfma_f32_16x16x32_f16(
                            ah[gt][kk], b0v, acc[gt], 0, 0, 0);
                        acc[gt] = __builtin_amdgcn_mfma_f32_16x16x32_f16(
                            ai[gt][kk], b1v, acc[gt], 0, 0, 0);
                    }
                }
            }
            if (lm < 8)
#pragma unroll
                for (int gt = 0; gt < 4; ++gt)
#pragma unroll
                    for (int r = 0; r < 4; ++r)
                        glp[wave][gt][quad * 4 + r][lm] = acc[gt][r];
            __syncthreads();
            if (tid < 128) {
                float gi = bias[0], gf = bias[1], gg = bias[2], go = bias[3];
#pragma unroll
                for (int w = 0; w < 4; ++w) {
                    gi += glp[w][0][ejj][eb]; gf += glp[w][1][ejj][eb];
                    gg += glp[w][2][ejj][eb]; go += glp[w][3][ejj][eb];
                }
                const float hn = lstm_cell(gi, gf, gg, go, c);
                const float ho = __shfl_xor(hn, 1);
                if (!(ejj & 1)) {
                    union { f16 h[2]; uint32_t u; } pk;
                    pk.h[0] = (f16)hn; pk.h[1] = (f16)ho;
                    ast(h1i + (size_t)(t & 1) * 2048 + (eb * H_ + jb + ejj) / 2, pk.u);
                }
                if (t == T_ - 1)
                    dout[(size_t)(b0 + eb) * H_ + jb + ejj] = hn;
            }
            __syncthreads();                       // drains h stores (vmcnt 0)
            if (tid == 0) ast(ownF + mem * 16, (uint32_t)(t + 1));
        }
    }
}

// ------------------------------------------------------------ launcher ------
extern "C" void kernel_launch(void* const* d_in, const int* in_sizes, int n_in,
                              void* d_out, int out_size, void* d_ws, size_t ws_size,
                              hipStream_t stream) {
    const float* x    = (const float*)d_in[0];
    const float* Wih0 = (const float*)d_in[1];
    const float* Whh0 = (const float*)d_in[2];
    const float* bih0 = (const float*)d_in[3];
    const float* bhh0 = (const float*)d_in[4];
    const float* mih0 = (const float*)d_in[5];
    const float* mhh0 = (const float*)d_in[6];
    const float* Wih1 = (const float*)d_in[7];
    const float* Whh1 = (const float*)d_in[8];
    const float* bih1 = (const float*)d_in[9];
    const float* bhh1 = (const float*)d_in[10];
    const float* mih1 = (const float*)d_in[11];
    const float* mhh1 = (const float*)d_in[12];

    char* ws = (char*)d_ws;
    uint32_t* flags = (uint32_t*)(ws + OFF_FLAGS);
    uint32_t* h0b   = (uint32_t*)(ws + OFF_H0B);
    uint32_t* h1b   = (uint32_t*)(ws + OFF_H1B);
    f16*   wih0 = (f16*)(ws + OFF_WIH0);
    f16*   whh0 = (f16*)(ws + OFF_WHH0);
    f16*   wih1 = (f16*)(ws + OFF_WIH1);
    f16*   whh1 = (f16*)(ws + OFF_WHH1);
    float* bs0  = (float*)(ws + OFF_B0);
    float* bs1  = (float*)(ws + OFF_B1);
    float* out  = (float*)d_out;

    // zero flags + h rings (ws is re-poisoned before every timed call)
    hipMemsetAsync(ws, 0, ZERO_BYTES, stream);

    k_maskw<<<512,  256, 0, stream>>>(Wih0, mih0, wih0, G_ * DIN_ / 4);
    k_maskw<<<1024, 256, 0, stream>>>(Whh0, mhh0, whh0, G_ * H_ / 4);
    k_maskw<<<1024, 256, 0, stream>>>(Wih1, mih1, wih1, G_ * H_ / 4);
    k_maskw<<<1024, 256, 0, stream>>>(Whh1, mhh1, whh1, G_ * H_ / 4);
    k_bias<<<8, 256, 0, stream>>>(bih0, bhh0, bs0);
    k_bias<<<8, 256, 0, stream>>>(bih1, bhh1, bs1);

    fused_rnn<<<512, 256, 0, stream>>>(x, wih0, whh0, bs0, wih1, whh1, bs1,
                                       out, h0b, h1b, flags);

    (void)in_sizes; (void)n_in; (void)out_size; (void)ws_size;
}